// Round 1
// baseline (186.199 us; speedup 1.0000x reference)
//
#include <hip/hip_runtime.h>

#define B_  8
#define TQ  256
#define TV  512
#define DD  256

__device__ __forceinline__ float fast_exp2(float x) {
#if __has_builtin(__builtin_amdgcn_exp2f)
  return __builtin_amdgcn_exp2f(x);
#else
  return __exp2f(x);
#endif
}
__device__ __forceinline__ float fast_rcp(float x) {
#if __has_builtin(__builtin_amdgcn_rcpf)
  return __builtin_amdgcn_rcpf(x);
#else
  return 1.0f / x;
#endif
}
// async 16B/lane global->LDS: LDS dest is wave-uniform base + lane*16
__device__ __forceinline__ void async_cp16(const float* g, float* l) {
  __builtin_amdgcn_global_load_lds(
      (const __attribute__((address_space(1))) unsigned int*)g,
      (__attribute__((address_space(3))) unsigned int*)l, 16, 0, 0);
}

// ---------------------------------------------------------------------------
// Kernel 1: out[M x 256] = scale * (A[M x 256] @ W[256 x 256] + bias)
// BM=BN=BK=64, 256 threads, 4x4 microtile per thread.
// ---------------------------------------------------------------------------
__global__ __launch_bounds__(256) void proj_kernel(
    const float* __restrict__ A, const float* __restrict__ W,
    const float* __restrict__ bias, float* __restrict__ out, float scale) {
  __shared__ float As[64][64];  // As[k][m] (transposed A tile)
  __shared__ float Bs[64][64];  // Bs[k][n]
  const int t  = threadIdx.x;
  const int bm = blockIdx.x * 64;
  const int bn = blockIdx.y * 64;
  const int tx = t & 15, ty = t >> 4;
  const int ar  = t & 63;         // A staging: row within tile (lane-major -> conflict-free LDS writes)
  const int acb = t >> 6;         // A staging: col-block base (0..3)
  const int br  = t >> 4;         // B staging: k-row base (0..15)
  const int bc  = (t & 15) << 2;  // B staging: col

  float acc[4][4] = {{0.f,0.f,0.f,0.f},{0.f,0.f,0.f,0.f},{0.f,0.f,0.f,0.f},{0.f,0.f,0.f,0.f}};

  for (int k0 = 0; k0 < 256; k0 += 64) {
#pragma unroll
    for (int i = 0; i < 4; ++i) {
      const int cb = acb + (i << 2);           // 0..15
      const int cc4 = cb << 2;                 // k-col
      float4 a = *(const float4*)(A + (size_t)(bm + ar) * 256 + k0 + cc4);
      As[cc4 + 0][ar] = a.x; As[cc4 + 1][ar] = a.y;
      As[cc4 + 2][ar] = a.z; As[cc4 + 3][ar] = a.w;
      const int kr = br + (i << 4);            // 0..63
      *(float4*)&Bs[kr][bc] = *(const float4*)(W + (size_t)(k0 + kr) * 256 + bn + bc);
    }
    __syncthreads();
#pragma unroll 8
    for (int k = 0; k < 64; ++k) {
      float4 av = *(const float4*)&As[k][ty << 2];
      float4 bv = *(const float4*)&Bs[k][tx << 2];
      acc[0][0] += av.x * bv.x; acc[0][1] += av.x * bv.y; acc[0][2] += av.x * bv.z; acc[0][3] += av.x * bv.w;
      acc[1][0] += av.y * bv.x; acc[1][1] += av.y * bv.y; acc[1][2] += av.y * bv.z; acc[1][3] += av.y * bv.w;
      acc[2][0] += av.z * bv.x; acc[2][1] += av.z * bv.y; acc[2][2] += av.z * bv.z; acc[2][3] += av.z * bv.w;
      acc[3][0] += av.w * bv.x; acc[3][1] += av.w * bv.y; acc[3][2] += av.w * bv.z; acc[3][3] += av.w * bv.w;
    }
    __syncthreads();
  }

  float4 bv = *(const float4*)&bias[bn + (tx << 2)];
#pragma unroll
  for (int r = 0; r < 4; ++r) {
    float4 o;
    o.x = scale * (acc[r][0] + bv.x);
    o.y = scale * (acc[r][1] + bv.y);
    o.z = scale * (acc[r][2] + bv.z);
    o.w = scale * (acc[r][3] + bv.w);
    *(float4*)(out + (size_t)(bm + (ty << 2) + r) * 256 + bn + (tx << 2)) = o;
  }
}

// ---------------------------------------------------------------------------
// Kernel 2: fused score + softmax + context + concat + transposed alignment.
// Grid: 512 blocks (b = blockIdx & 7 for XCD locality, 4 q-rows per block).
// 256 threads = 4 waves; wave w owns q-row i0+w; lane owns one j per chunk.
// q', v' are pre-scaled by 2*log2(e):  score = 256 - 2 * sum_d 1/(1+exp2(q'+v'))
// ---------------------------------------------------------------------------
__global__ __launch_bounds__(256, 2) void attn_kernel(
    const float* __restrict__ qp, const float* __restrict__ vp,
    const float* __restrict__ value, const float* __restrict__ query,
    float* __restrict__ out1, float* __restrict__ out2) {
  __shared__ float vs[64][260];   // v' chunk, +4 pad to break stride-256 bank aliasing
  __shared__ float qsh[4][256];   // 4 q' rows (broadcast reads -> no pad needed)
  __shared__ float alg[4][512];   // alignment rows

  const int t    = threadIdx.x;
  const int lane = t & 63;
  const int wv   = t >> 6;
  const int bb   = blockIdx.x & 7;
  const int i0   = (blockIdx.x >> 3) << 2;

  // stage the 4 q' rows (one async row per wave)
  async_cp16(qp + (size_t)(bb * TQ + i0 + wv) * DD + lane * 4, &qsh[wv][0]);

  const float* vpb = vp + (size_t)bb * TV * DD;
  float sreg[8];

#pragma unroll
  for (int c = 0; c < 8; ++c) {
#pragma unroll
    for (int r = 0; r < 16; ++r) {
      const int j = (wv << 4) + r;
      async_cp16(vpb + (size_t)(c * 64 + j) * DD + lane * 4, &vs[j][0]);
    }
    __syncthreads();  // drains vmcnt for global_load_lds

    float acc = 0.f;
#pragma unroll 2
    for (int d = 0; d < DD; d += 4) {
      float4 qv = *(const float4*)&qsh[wv][d];
      float4 vv = *(const float4*)&vs[lane][d];
      float r0 = fast_rcp(1.f + fast_exp2(qv.x + vv.x));
      float r1 = fast_rcp(1.f + fast_exp2(qv.y + vv.y));
      float r2 = fast_rcp(1.f + fast_exp2(qv.z + vv.z));
      float r3 = fast_rcp(1.f + fast_exp2(qv.w + vv.w));
      acc += (r0 + r1) + (r2 + r3);
    }
    sreg[c] = acc;
    __syncthreads();  // protect vs before next chunk overwrites
  }

  // ---- softmax over j (row i0+wv spread across 64 lanes x 8 regs) ----
  // score = 256 - 2*S  ->  max(score) <-> min(S);  w = exp2(c*(Smin - S))
  float mn = sreg[0];
#pragma unroll
  for (int c = 1; c < 8; ++c) mn = fminf(mn, sreg[c]);
#pragma unroll
  for (int m = 1; m < 64; m <<= 1) mn = fminf(mn, __shfl_xor(mn, m, 64));

  const float CC = 2.8853900817779268f;  // 2*log2(e)
  float p[8];
  float sum = 0.f;
#pragma unroll
  for (int c = 0; c < 8; ++c) { p[c] = fast_exp2(CC * (mn - sreg[c])); sum += p[c]; }
#pragma unroll
  for (int m = 1; m < 64; m <<= 1) sum += __shfl_xor(sum, m, 64);
  const float inv = fast_rcp(sum);
#pragma unroll
  for (int c = 0; c < 8; ++c) alg[wv][c * 64 + lane] = p[c] * inv;
  __syncthreads();

  // ---- alignment_t write: out2[b][j][i0..i0+3], float4 per j ----
#pragma unroll
  for (int jj = 0; jj < 2; ++jj) {
    const int j = jj * 256 + t;
    float4 av = make_float4(alg[0][j], alg[1][j], alg[2][j], alg[3][j]);
    *(float4*)(out2 + (size_t)(bb * TV + j) * TQ + i0) = av;
  }

  // ---- context: thread t owns feature dd = t for all 4 rows ----
  float c0 = 0.f, c1 = 0.f, c2 = 0.f, c3 = 0.f;
  const float* vb = value + (size_t)bb * TV * DD;
#pragma unroll 2
  for (int j = 0; j < TV; j += 4) {
    float v0 = vb[(size_t)(j + 0) * DD + t];
    float v1 = vb[(size_t)(j + 1) * DD + t];
    float v2 = vb[(size_t)(j + 2) * DD + t];
    float v3 = vb[(size_t)(j + 3) * DD + t];
    float4 a0 = *(const float4*)&alg[0][j];
    float4 a1 = *(const float4*)&alg[1][j];
    float4 a2 = *(const float4*)&alg[2][j];
    float4 a3 = *(const float4*)&alg[3][j];
    c0 += a0.x * v0 + a0.y * v1 + a0.z * v2 + a0.w * v3;
    c1 += a1.x * v0 + a1.y * v1 + a1.z * v2 + a1.w * v3;
    c2 += a2.x * v0 + a2.y * v1 + a2.z * v2 + a2.w * v3;
    c3 += a3.x * v0 + a3.y * v1 + a3.z * v2 + a3.w * v3;
  }

  // ---- context-concat output: [ctx | query] per row ----
  const float* qg = query + (size_t)(bb * TQ + i0) * DD;
  float* o = out1 + (size_t)(bb * TQ + i0) * (2 * DD);
  o[0 * 512 + t] = c0; o[0 * 512 + 256 + t] = qg[0 * DD + t];
  o[1 * 512 + t] = c1; o[1 * 512 + 256 + t] = qg[1 * DD + t];
  o[2 * 512 + t] = c2; o[2 * 512 + 256 + t] = qg[2 * DD + t];
  o[3 * 512 + t] = c3; o[3 * 512 + 256 + t] = qg[3 * DD + t];
}

// ---------------------------------------------------------------------------
extern "C" void kernel_launch(void* const* d_in, const int* in_sizes, int n_in,
                              void* d_out, int out_size, void* d_ws, size_t ws_size,
                              hipStream_t stream) {
  const float* query = (const float*)d_in[0];  // [8,256,256]
  const float* value = (const float*)d_in[1];  // [8,512,256]
  const float* W1    = (const float*)d_in[2];  // [256,256]
  const float* b1    = (const float*)d_in[3];  // [256]
  const float* W2    = (const float*)d_in[4];  // [256,256]
  const float* b2    = (const float*)d_in[5];  // [256]

  float* out1 = (float*)d_out;                     // context concat [8,256,512]
  float* out2 = out1 + (size_t)B_ * TQ * 2 * DD;   // alignment_t   [8,512,256]

  float* qp = (float*)d_ws;                        // q' scaled: 2048*256 floats
  float* vp = qp + (size_t)B_ * TQ * DD;           // v' scaled: 4096*256 floats

  const float SC = 2.8853900817779268f;  // 2*log2(e): exp(2x) = exp2(SC*x)

  proj_kernel<<<dim3((B_ * TQ) / 64, 4), 256, 0, stream>>>(query, W1, b1, qp, SC);
  proj_kernel<<<dim3((B_ * TV) / 64, 4), 256, 0, stream>>>(value, W2, b2, vp, SC);
  attn_kernel<<<dim3(B_ * (TQ / 4)), 256, 0, stream>>>(qp, vp, value, query, out1, out2);
}

// Round 2
// 172.596 us; speedup vs baseline: 1.0788x; 1.0788x over previous
//
#include <hip/hip_runtime.h>

#define B_  8
#define TQ  256
#define TV  512
#define DD  256

__device__ __forceinline__ float fast_exp2(float x) {
#if __has_builtin(__builtin_amdgcn_exp2f)
  return __builtin_amdgcn_exp2f(x);
#else
  return __exp2f(x);
#endif
}
__device__ __forceinline__ float fast_rcp(float x) {
#if __has_builtin(__builtin_amdgcn_rcpf)
  return __builtin_amdgcn_rcpf(x);
#else
  return 1.0f / x;
#endif
}
// async 16B/lane global->LDS: LDS dest is wave-uniform base + lane*16
__device__ __forceinline__ void async_cp16(const float* g, float* l) {
  __builtin_amdgcn_global_load_lds(
      (const __attribute__((address_space(1))) unsigned int*)g,
      (__attribute__((address_space(3))) unsigned int*)l, 16, 0, 0);
}

// ---------------------------------------------------------------------------
// Fused projections: q' = SC*(query@W1 + b1), v' = SC*(value@W2 + b2).
// One kernel, wave-uniform branch on row tile. BM=32, BN=64, BK=64,
// 256 threads, 2x4 microtile -> 768 blocks (3 blocks/CU).
// ---------------------------------------------------------------------------
__global__ __launch_bounds__(256) void proj_fused(
    const float* __restrict__ query, const float* __restrict__ value,
    const float* __restrict__ W1, const float* __restrict__ b1,
    const float* __restrict__ W2, const float* __restrict__ b2,
    float* __restrict__ qp, float* __restrict__ vp, float scale) {
  __shared__ float As[64][33];  // As[k][m], +1 pad
  __shared__ float Bs[64][64];  // Bs[k][n]
  const int t  = threadIdx.x;
  const int rt = blockIdx.x;
  const int bn = blockIdx.y * 64;

  const float* A; const float* W; const float* bias; float* out; int row0;
  if (rt < 64) { row0 = rt * 32;        A = query; W = W1; bias = b1; out = qp; }
  else         { row0 = (rt - 64) * 32; A = value; W = W2; bias = b2; out = vp; }

  const int tx = t & 15, ty = t >> 4;
  const int arow = t >> 3, acol = (t & 7) << 3;   // A stage: 8 floats/thread
  const int brow = t >> 2, bcol = (t & 3) << 4;   // B stage: 16 floats/thread

  float acc[2][4] = {{0.f,0.f,0.f,0.f},{0.f,0.f,0.f,0.f}};

  for (int k0 = 0; k0 < 256; k0 += 64) {
    float4 a0 = *(const float4*)(A + (size_t)(row0 + arow) * DD + k0 + acol);
    float4 a1 = *(const float4*)(A + (size_t)(row0 + arow) * DD + k0 + acol + 4);
    As[acol + 0][arow] = a0.x; As[acol + 1][arow] = a0.y;
    As[acol + 2][arow] = a0.z; As[acol + 3][arow] = a0.w;
    As[acol + 4][arow] = a1.x; As[acol + 5][arow] = a1.y;
    As[acol + 6][arow] = a1.z; As[acol + 7][arow] = a1.w;
#pragma unroll
    for (int h = 0; h < 4; ++h)
      *(float4*)&Bs[brow][bcol + (h << 2)] =
          *(const float4*)(W + (size_t)(k0 + brow) * DD + bn + bcol + (h << 2));
    __syncthreads();
#pragma unroll 16
    for (int k = 0; k < 64; ++k) {
      float2 av = *(const float2*)&As[k][ty << 1];
      float4 bv = *(const float4*)&Bs[k][tx << 2];
      acc[0][0] = fmaf(av.x, bv.x, acc[0][0]); acc[0][1] = fmaf(av.x, bv.y, acc[0][1]);
      acc[0][2] = fmaf(av.x, bv.z, acc[0][2]); acc[0][3] = fmaf(av.x, bv.w, acc[0][3]);
      acc[1][0] = fmaf(av.y, bv.x, acc[1][0]); acc[1][1] = fmaf(av.y, bv.y, acc[1][1]);
      acc[1][2] = fmaf(av.y, bv.z, acc[1][2]); acc[1][3] = fmaf(av.y, bv.w, acc[1][3]);
    }
    __syncthreads();
  }

  float4 bvv = *(const float4*)&bias[bn + (tx << 2)];
#pragma unroll
  for (int r = 0; r < 2; ++r) {
    float4 o;
    o.x = scale * (acc[r][0] + bvv.x);
    o.y = scale * (acc[r][1] + bvv.y);
    o.z = scale * (acc[r][2] + bvv.z);
    o.w = scale * (acc[r][3] + bvv.w);
    *(float4*)(out + (size_t)(row0 + (ty << 1) + r) * DD + bn + (tx << 2)) = o;
  }
}

// ---------------------------------------------------------------------------
// Fused score + softmax + context + concat + transposed alignment.
// 512 blocks, 256 threads (4 waves), LDS 28.9 KB -> 5 blocks/CU.
// Per chunk: 16 v'-rows in LDS; lane = (jj = lane&15 -> j, dq = lane>>4 ->
// d-quarter); reduce over d-quarters with 2 shfl_xor; raw scores -> alg LDS.
// score = 256 - 2*S with S = sum_d 1/(1+exp2(q'+v')) (inputs pre-scaled).
// ---------------------------------------------------------------------------
__global__ __launch_bounds__(256, 5) void attn_kernel(
    const float* __restrict__ qp, const float* __restrict__ vp,
    const float* __restrict__ value, const float* __restrict__ query,
    float* __restrict__ out1, float* __restrict__ out2) {
  __shared__ float vs[16][260];   // v' chunk (stride 260: 8-lane-phase conflict-free)
  __shared__ float qsh[4][256];   // 4 q' rows (broadcast reads)
  __shared__ float alg[4][512];   // raw scores, then normalized alignment

  const int t    = threadIdx.x;
  const int lane = t & 63;
  const int wv   = t >> 6;
  const int bb   = blockIdx.x & 7;          // batch -> XCD locality
  const int i0   = (blockIdx.x >> 3) << 2;  // first q-row of this block
  const int jj   = lane & 15;               // j within chunk
  const int dq   = lane >> 4;               // d-quarter

  async_cp16(qp + (size_t)(bb * TQ + i0 + wv) * DD + lane * 4, &qsh[wv][0]);

  const float* vpb = vp + (size_t)bb * TV * DD;

  for (int c = 0; c < 32; ++c) {
#pragma unroll
    for (int r = 0; r < 4; ++r) {
      const int j = (wv << 2) + r;
      async_cp16(vpb + (size_t)((c << 4) + j) * DD + lane * 4, &vs[j][0]);
    }
    __syncthreads();  // drains vmcnt for global_load_lds

    float acc = 0.f;
#pragma unroll
    for (int d16 = 0; d16 < 16; ++d16) {
      const int d = (dq << 6) + (d16 << 2);
      float4 q4 = *(const float4*)&qsh[wv][d];
      float4 v4 = *(const float4*)&vs[jj][d];
      float r0 = fast_rcp(1.f + fast_exp2(q4.x + v4.x));
      float r1 = fast_rcp(1.f + fast_exp2(q4.y + v4.y));
      float r2 = fast_rcp(1.f + fast_exp2(q4.z + v4.z));
      float r3 = fast_rcp(1.f + fast_exp2(q4.w + v4.w));
      acc += (r0 + r1) + (r2 + r3);
    }
    acc += __shfl_xor(acc, 16, 64);
    acc += __shfl_xor(acc, 32, 64);
    if (lane < 16) alg[wv][(c << 4) + jj] = acc;
    __syncthreads();  // protect vs before next chunk overwrites
  }

  // ---- softmax over j (row i0+wv; S in alg[wv][0..511]) ----
  // score = 256 - 2*S  ->  max(score) <-> min(S);  w = exp2(CC*(Smin - S))
  float s[8];
#pragma unroll
  for (int c = 0; c < 8; ++c) s[c] = alg[wv][(c << 6) + lane];
  float mn = s[0];
#pragma unroll
  for (int c = 1; c < 8; ++c) mn = fminf(mn, s[c]);
#pragma unroll
  for (int m = 1; m < 64; m <<= 1) mn = fminf(mn, __shfl_xor(mn, m, 64));

  const float CC = 2.8853900817779268f;  // 2*log2(e)
  float p[8];
  float sum = 0.f;
#pragma unroll
  for (int c = 0; c < 8; ++c) { p[c] = fast_exp2(CC * (mn - s[c])); sum += p[c]; }
#pragma unroll
  for (int m = 1; m < 64; m <<= 1) sum += __shfl_xor(sum, m, 64);
  const float inv = fast_rcp(sum);
#pragma unroll
  for (int c = 0; c < 8; ++c) alg[wv][(c << 6) + lane] = p[c] * inv;
  __syncthreads();

  // ---- alignment_t write: out2[b][j][i0..i0+3], float4 per j ----
#pragma unroll
  for (int jg = 0; jg < 2; ++jg) {
    const int j = (jg << 8) + t;
    float4 av = make_float4(alg[0][j], alg[1][j], alg[2][j], alg[3][j]);
    *(float4*)(out2 + (size_t)(bb * TV + j) * TQ + i0) = av;
  }

  // ---- context: thread t owns feature d = t for all 4 rows ----
  float c0 = 0.f, c1 = 0.f, c2 = 0.f, c3 = 0.f;
  const float* vb = value + (size_t)bb * TV * DD;
#pragma unroll 2
  for (int j = 0; j < TV; j += 4) {
    float v0 = vb[(size_t)(j + 0) * DD + t];
    float v1 = vb[(size_t)(j + 1) * DD + t];
    float v2 = vb[(size_t)(j + 2) * DD + t];
    float v3 = vb[(size_t)(j + 3) * DD + t];
    float4 a0 = *(const float4*)&alg[0][j];
    float4 a1 = *(const float4*)&alg[1][j];
    float4 a2 = *(const float4*)&alg[2][j];
    float4 a3 = *(const float4*)&alg[3][j];
    c0 += a0.x * v0 + a0.y * v1 + a0.z * v2 + a0.w * v3;
    c1 += a1.x * v0 + a1.y * v1 + a1.z * v2 + a1.w * v3;
    c2 += a2.x * v0 + a2.y * v1 + a2.z * v2 + a2.w * v3;
    c3 += a3.x * v0 + a3.y * v1 + a3.z * v2 + a3.w * v3;
  }

  // ---- context-concat output: [ctx | query] per row ----
  const float* qg = query + (size_t)(bb * TQ + i0) * DD;
  float* o = out1 + (size_t)(bb * TQ + i0) * (2 * DD);
  o[0 * 512 + t] = c0; o[0 * 512 + 256 + t] = qg[0 * DD + t];
  o[1 * 512 + t] = c1; o[1 * 512 + 256 + t] = qg[1 * DD + t];
  o[2 * 512 + t] = c2; o[2 * 512 + 256 + t] = qg[2 * DD + t];
  o[3 * 512 + t] = c3; o[3 * 512 + 256 + t] = qg[3 * DD + t];
}

// ---------------------------------------------------------------------------
extern "C" void kernel_launch(void* const* d_in, const int* in_sizes, int n_in,
                              void* d_out, int out_size, void* d_ws, size_t ws_size,
                              hipStream_t stream) {
  const float* query = (const float*)d_in[0];  // [8,256,256]
  const float* value = (const float*)d_in[1];  // [8,512,256]
  const float* W1    = (const float*)d_in[2];  // [256,256]
  const float* b1    = (const float*)d_in[3];  // [256]
  const float* W2    = (const float*)d_in[4];  // [256,256]
  const float* b2    = (const float*)d_in[5];  // [256]

  float* out1 = (float*)d_out;                     // context concat [8,256,512]
  float* out2 = out1 + (size_t)B_ * TQ * 2 * DD;   // alignment_t   [8,512,256]

  float* qp = (float*)d_ws;                        // q' scaled: 2048*256 floats
  float* vp = qp + (size_t)B_ * TQ * DD;           // v' scaled: 4096*256 floats

  const float SC = 2.8853900817779268f;  // 2*log2(e): exp(2x) = exp2(SC*x)

  proj_fused<<<dim3(192, 4), 256, 0, stream>>>(query, value, W1, b1, W2, b2, qp, vp, SC);
  attn_kernel<<<dim3(B_ * (TQ / 4)), 256, 0, stream>>>(qp, vp, value, query, out1, out2);
}

// Round 3
// 166.302 us; speedup vs baseline: 1.1196x; 1.0378x over previous
//
#include <hip/hip_runtime.h>

#define B_  8
#define TQ  256
#define TV  512
#define DD  256

__device__ __forceinline__ float fast_exp2(float x) {
#if __has_builtin(__builtin_amdgcn_exp2f)
  return __builtin_amdgcn_exp2f(x);
#else
  return __exp2f(x);
#endif
}
__device__ __forceinline__ float fast_rcp(float x) {
#if __has_builtin(__builtin_amdgcn_rcpf)
  return __builtin_amdgcn_rcpf(x);
#else
  return 1.0f / x;
#endif
}
// async 16B/lane global->LDS: LDS dest is wave-uniform base + lane*16
__device__ __forceinline__ void async_cp16(const float* g, float* l) {
  __builtin_amdgcn_global_load_lds(
      (const __attribute__((address_space(1))) unsigned int*)g,
      (__attribute__((address_space(3))) unsigned int*)l, 16, 0, 0);
}

// ---------------------------------------------------------------------------
// Fused projections: q' = SC*(query@W1 + b1), v' = SC*(value@W2 + b2).
// One kernel, wave-uniform branch on row tile. BM=32, BN=64, BK=64,
// 256 threads, 2x4 microtile -> 768 blocks (3 blocks/CU).
// ---------------------------------------------------------------------------
__global__ __launch_bounds__(256) void proj_fused(
    const float* __restrict__ query, const float* __restrict__ value,
    const float* __restrict__ W1, const float* __restrict__ b1,
    const float* __restrict__ W2, const float* __restrict__ b2,
    float* __restrict__ qp, float* __restrict__ vp, float scale) {
  __shared__ float As[64][33];  // As[k][m], +1 pad
  __shared__ float Bs[64][64];  // Bs[k][n]
  const int t  = threadIdx.x;
  const int rt = blockIdx.x;
  const int bn = blockIdx.y * 64;

  const float* A; const float* W; const float* bias; float* out; int row0;
  if (rt < 64) { row0 = rt * 32;        A = query; W = W1; bias = b1; out = qp; }
  else         { row0 = (rt - 64) * 32; A = value; W = W2; bias = b2; out = vp; }

  const int tx = t & 15, ty = t >> 4;
  const int arow = t >> 3, acol = (t & 7) << 3;   // A stage: 8 floats/thread
  const int brow = t >> 2, bcol = (t & 3) << 4;   // B stage: 16 floats/thread

  float acc[2][4] = {{0.f,0.f,0.f,0.f},{0.f,0.f,0.f,0.f}};

  for (int k0 = 0; k0 < 256; k0 += 64) {
    float4 a0 = *(const float4*)(A + (size_t)(row0 + arow) * DD + k0 + acol);
    float4 a1 = *(const float4*)(A + (size_t)(row0 + arow) * DD + k0 + acol + 4);
    As[acol + 0][arow] = a0.x; As[acol + 1][arow] = a0.y;
    As[acol + 2][arow] = a0.z; As[acol + 3][arow] = a0.w;
    As[acol + 4][arow] = a1.x; As[acol + 5][arow] = a1.y;
    As[acol + 6][arow] = a1.z; As[acol + 7][arow] = a1.w;
#pragma unroll
    for (int h = 0; h < 4; ++h)
      *(float4*)&Bs[brow][bcol + (h << 2)] =
          *(const float4*)(W + (size_t)(k0 + brow) * DD + bn + bcol + (h << 2));
    __syncthreads();
#pragma unroll 16
    for (int k = 0; k < 64; ++k) {
      float2 av = *(const float2*)&As[k][ty << 1];
      float4 bv = *(const float4*)&Bs[k][tx << 2];
      acc[0][0] = fmaf(av.x, bv.x, acc[0][0]); acc[0][1] = fmaf(av.x, bv.y, acc[0][1]);
      acc[0][2] = fmaf(av.x, bv.z, acc[0][2]); acc[0][3] = fmaf(av.x, bv.w, acc[0][3]);
      acc[1][0] = fmaf(av.y, bv.x, acc[1][0]); acc[1][1] = fmaf(av.y, bv.y, acc[1][1]);
      acc[1][2] = fmaf(av.y, bv.z, acc[1][2]); acc[1][3] = fmaf(av.y, bv.w, acc[1][3]);
    }
    __syncthreads();
  }

  float4 bvv = *(const float4*)&bias[bn + (tx << 2)];
#pragma unroll
  for (int r = 0; r < 2; ++r) {
    float4 o;
    o.x = scale * (acc[r][0] + bvv.x);
    o.y = scale * (acc[r][1] + bvv.y);
    o.z = scale * (acc[r][2] + bvv.z);
    o.w = scale * (acc[r][3] + bvv.w);
    *(float4*)(out + (size_t)(row0 + (ty << 1) + r) * DD + bn + (tx << 2)) = o;
  }
}

// ---------------------------------------------------------------------------
// Fused score + softmax + context + concat + transposed alignment.
// 512 blocks x 512 threads (8 waves). LDS 78848 B -> 2 blocks/CU -> 16
// waves/CU (50% occupancy cap; grid = exactly 2 blocks/CU).
// Wave wv = (r = wv&3 -> q-row, h = wv>>2 -> d-half). lane = j within the
// 64-row chunk (round-1 zero-conflict pattern: stride 260, +128-float half
// offset is bank-invariant). d-half partials exchanged via the dead vs
// buffer; softmax computed redundantly by both half-waves.
// score = 256 - 2*S with S = sum_d 1/(1+exp2(q'+v')) (inputs pre-scaled).
// ---------------------------------------------------------------------------
__global__ __launch_bounds__(512, 4) void attn_kernel(
    const float* __restrict__ qp, const float* __restrict__ vp,
    const float* __restrict__ value, const float* __restrict__ query,
    float* __restrict__ out1, float* __restrict__ out2) {
  __shared__ float vs[64][260];   // v' chunk; also reused as the 8x512 partial-score exchange
  __shared__ float qsh[4][256];   // 4 q' rows (broadcast reads)
  __shared__ float alg[4][512];   // normalized alignment

  const int t    = threadIdx.x;
  const int lane = t & 63;
  const int wv   = t >> 6;        // 0..7
  const int rr   = wv & 3;        // q-row within block
  const int hh   = wv >> 2;       // d-half
  const int hbase = hh << 7;      // 0 or 128
  const int bb   = blockIdx.x & 7;          // batch -> XCD locality
  const int i0   = (blockIdx.x >> 3) << 2;  // first q-row of this block

  // stage the 4 q' rows (one async row per wave, waves 0..3)
  if (wv < 4)
    async_cp16(qp + (size_t)(bb * TQ + i0 + wv) * DD + lane * 4, &qsh[wv][0]);

  const float* vpb = vp + (size_t)bb * TV * DD;
  float sreg[8];

  for (int c = 0; c < 8; ++c) {
#pragma unroll
    for (int r = 0; r < 8; ++r) {
      const int j = (wv << 3) + r;
      async_cp16(vpb + (size_t)((c << 6) + j) * DD + lane * 4, &vs[j][0]);
    }
    __syncthreads();  // drains vmcnt for global_load_lds

    float acc = 0.f;
#pragma unroll 4
    for (int d4 = 0; d4 < 32; ++d4) {
      const int d = hbase + (d4 << 2);
      float4 q4 = *(const float4*)&qsh[rr][d];
      float4 v4 = *(const float4*)&vs[lane][d];
      float r0 = fast_rcp(1.f + fast_exp2(q4.x + v4.x));
      float r1 = fast_rcp(1.f + fast_exp2(q4.y + v4.y));
      float r2 = fast_rcp(1.f + fast_exp2(q4.z + v4.z));
      float r3 = fast_rcp(1.f + fast_exp2(q4.w + v4.w));
      acc += (r0 + r1) + (r2 + r3);
    }
    sreg[c] = acc;
    __syncthreads();  // protect vs before next chunk overwrites
  }

  // ---- exchange d-half partials through the (dead) vs buffer ----
  float* sx = &vs[0][0];  // 8 rows x 512 = 16 KB <= vs
#pragma unroll
  for (int c = 0; c < 8; ++c) sx[(wv << 9) + (c << 6) + lane] = sreg[c];
  __syncthreads();

  // ---- softmax over j (row rr; redundant across the two half-waves) ----
  // score = 256 - 2*S  ->  max(score) <-> min(S);  w = exp2(CC*(Smin - S))
  float s[8];
#pragma unroll
  for (int c = 0; c < 8; ++c)
    s[c] = sx[(rr << 9) + (c << 6) + lane] + sx[((rr + 4) << 9) + (c << 6) + lane];
  float mn = s[0];
#pragma unroll
  for (int c = 1; c < 8; ++c) mn = fminf(mn, s[c]);
#pragma unroll
  for (int m = 1; m < 64; m <<= 1) mn = fminf(mn, __shfl_xor(mn, m, 64));

  const float CC = 2.8853900817779268f;  // 2*log2(e)
  float p[8];
  float sum = 0.f;
#pragma unroll
  for (int c = 0; c < 8; ++c) { p[c] = fast_exp2(CC * (mn - s[c])); sum += p[c]; }
#pragma unroll
  for (int m = 1; m < 64; m <<= 1) sum += __shfl_xor(sum, m, 64);
  const float inv = fast_rcp(sum);
  if (hh == 0) {
#pragma unroll
    for (int c = 0; c < 8; ++c) alg[rr][(c << 6) + lane] = p[c] * inv;
  }
  __syncthreads();

  // ---- alignment_t write: out2[b][j][i0..i0+3], one float4 per thread ----
  {
    const int j = t;  // 0..511
    float4 av = make_float4(alg[0][j], alg[1][j], alg[2][j], alg[3][j]);
    *(float4*)(out2 + (size_t)(bb * TV + j) * TQ + i0) = av;
  }

  // ---- context: thread t owns (feature f, row-pair rp) ----
  const int f  = t & 255;
  const int rp = t >> 8;          // 0 or 1 -> rows 2rp, 2rp+1
  float c0 = 0.f, c1 = 0.f;
  const float* vb = value + (size_t)bb * TV * DD;
  const float* a0p = &alg[(rp << 1) + 0][0];
  const float* a1p = &alg[(rp << 1) + 1][0];
#pragma unroll 2
  for (int j = 0; j < TV; j += 4) {
    float v0 = vb[(size_t)(j + 0) * DD + f];
    float v1 = vb[(size_t)(j + 1) * DD + f];
    float v2 = vb[(size_t)(j + 2) * DD + f];
    float v3 = vb[(size_t)(j + 3) * DD + f];
    float4 a0 = *(const float4*)&a0p[j];
    float4 a1 = *(const float4*)&a1p[j];
    c0 += a0.x * v0 + a0.y * v1 + a0.z * v2 + a0.w * v3;
    c1 += a1.x * v0 + a1.y * v1 + a1.z * v2 + a1.w * v3;
  }

  // ---- context-concat output: [ctx | query] per row ----
  const int r0 = (rp << 1), r1 = r0 + 1;
  const float* qg = query + (size_t)(bb * TQ + i0) * DD;
  float* o = out1 + (size_t)(bb * TQ + i0) * (2 * DD);
  o[r0 * 512 + f] = c0; o[r0 * 512 + 256 + f] = qg[r0 * DD + f];
  o[r1 * 512 + f] = c1; o[r1 * 512 + 256 + f] = qg[r1 * DD + f];
}

// ---------------------------------------------------------------------------
extern "C" void kernel_launch(void* const* d_in, const int* in_sizes, int n_in,
                              void* d_out, int out_size, void* d_ws, size_t ws_size,
                              hipStream_t stream) {
  const float* query = (const float*)d_in[0];  // [8,256,256]
  const float* value = (const float*)d_in[1];  // [8,512,256]
  const float* W1    = (const float*)d_in[2];  // [256,256]
  const float* b1    = (const float*)d_in[3];  // [256]
  const float* W2    = (const float*)d_in[4];  // [256,256]
  const float* b2    = (const float*)d_in[5];  // [256]

  float* out1 = (float*)d_out;                     // context concat [8,256,512]
  float* out2 = out1 + (size_t)B_ * TQ * 2 * DD;   // alignment_t   [8,512,256]

  float* qp = (float*)d_ws;                        // q' scaled: 2048*256 floats
  float* vp = qp + (size_t)B_ * TQ * DD;           // v' scaled: 4096*256 floats

  const float SC = 2.8853900817779268f;  // 2*log2(e): exp(2x) = exp2(SC*x)

  proj_fused<<<dim3(192, 4), 256, 0, stream>>>(query, value, W1, b1, W2, b2, qp, vp, SC);
  attn_kernel<<<dim3(B_ * (TQ / 4)), 512, 0, stream>>>(qp, vp, value, query, out1, out2);
}